// Round 19
// baseline (19.785 us; speedup 1.0000x reference)
//
#include <hip/hip_runtime.h>
#include <hip/hip_bf16.h>
#include <math.h>

// MACE equivariant score head — 2 nodes, z-form with pre-transposed W~.
// Dead code: Wss (d_in[5]), Wvv (d_in[7]) — s3=silu(s2) is deleted in the reference.
//
// out[n,m] = sum_c vraw[n,c,m] * h[n,c],  h[n,c] = sum_u z_aug[n,u]*E[u,c]
//   z_aug[n,u] = t[n]*wtld[u] + sum_q s[n,q] * W1s[16+q,u]
//   wtld[u]    = sum_{p<16} Wt[p] * W1s[p,u]
//   E[u,c] = scale * sum_v D[u,v]*W1v[c,v],  D[u,v] = dot(Wsv[u,v,:], W2)
//   scale  = 1/(S*V*sqrt(V))
//
// kE node (146 blocks): [0,144) verified E-producer -> Et[c][u] bf16.
//   [144,146): W~ transpose blocks -> W1tb[u][q] bf16. No LDS: reads of
//   W1s at fixed q / varying u are CONTIGUOUS (coalesced); strided u32
//   writes go to L2 (37KB total). Hidden under kE's HBM stream.
// k4c (256 blocks, 16 rows): R17's verified z-form (absmax 0.0156) with the
//   conflict-ridden in-kernel transpose replaced by uint4 staging of W1tb.
//   LDS 54KB -> 2 blocks/CU, 8 waves; 22 MFMA/wave.

#define S 144
#define V 128

typedef __attribute__((ext_vector_type(8))) short bf16x8;
typedef __attribute__((ext_vector_type(4))) float f32x4;

__device__ inline unsigned short f2bf(float x) {
    const __hip_bfloat16 h = __float2bfloat16(x);
    return *(const unsigned short*)&h;
}

// ---------------- kE node: E-blocks + W~-transpose blocks ----------------
__global__ __launch_bounds__(256) void kE(const float* __restrict__ Wsv,
                                          const float* __restrict__ W2,
                                          const float* __restrict__ W1v,
                                          const float* __restrict__ W1s,
                                          unsigned short* __restrict__ Et,
                                          unsigned* __restrict__ W1tb32) {
    __shared__ float Dsh[V];
    __shared__ float Epart[2][V];
    const int tid = threadIdx.x;
    const int wave = tid >> 6;
    const int lane = tid & 63;

    if (blockIdx.x < S) {
        // ---- E-block: u = blockIdx.x (verified R16) ----
        const int half = lane >> 5;
        const int j = lane & 31;
        const int u = blockIdx.x;
        const float4* Wsv4 = (const float4*)Wsv;
        const float4 w4 = ((const float4*)W2)[j];
        const size_t base4 = ((size_t)u * V + 32 * wave) * 32;
        float4 a[16];
#pragma unroll
        for (int i = 0; i < 16; ++i)
            a[i] = Wsv4[base4 + (size_t)(2 * i + half) * 32 + j];
#pragma unroll
        for (int i = 0; i < 16; ++i) {
            float acc = a[i].x * w4.x + a[i].y * w4.y + a[i].z * w4.z + a[i].w * w4.w;
#pragma unroll
            for (int off = 1; off < 32; off <<= 1)
                acc += __shfl_xor(acc, off, 64);
            if (j == 0) Dsh[32 * wave + 2 * i + half] = acc;
        }
        __syncthreads();
        const int c = tid & 127, vh = tid >> 7;
        const float4* W1v4 = (const float4*)W1v;
        const float4* D4 = (const float4*)Dsh;
        float acc = 0.f;
#pragma unroll
        for (int i = 0; i < 16; ++i) {
            const float4 wv = W1v4[c * 32 + vh * 16 + i];
            const float4 dv = D4[vh * 16 + i];
            acc += wv.x * dv.x + wv.y * dv.y + wv.z * dv.z + wv.w * dv.w;
        }
        Epart[vh][c] = acc;
        __syncthreads();
        if (tid < V) {
            const float scale = 1.0f / (144.0f * 128.0f * sqrtf(128.0f));
            Et[(size_t)tid * S + blockIdx.x] =
                f2bf(scale * (Epart[0][tid] + Epart[1][tid]));
        }
    } else {
        // ---- transpose block: W1tb[u][q] = bf16(W1s[16+q][u]) ----
        // reads at fixed q / varying u are contiguous -> coalesced; no LDS.
        const int b = blockIdx.x - S;   // 0 or 1
#pragma unroll
        for (int i = 0; i < 18; ++i) {
            const int jj = b * 4608 + tid + 256 * i;   // [0, 9216)
            const int qp = jj / 144;                   // q-pair 0..63
            const int u = jj - qp * 144;
            const float a0 = W1s[(size_t)(16 + 2 * qp) * S + u];
            const float a1 = W1s[(size_t)(16 + 2 * qp + 1) * S + u];
            const __hip_bfloat162 p = __float22bfloat162_rn(make_float2(a0, a1));
            W1tb32[u * 64 + qp] = *(const unsigned*)&p;
        }
    }
}

// ---------------- k4c: z-GEMM + h-GEMM + epilogue (R17-verified arithmetic) ----------------
__global__ __launch_bounds__(256) void k4c(const float* __restrict__ feat,
                                           const float* __restrict__ times,
                                           const float* __restrict__ Wt,
                                           const float* __restrict__ W1s,
                                           const unsigned short* __restrict__ EtG,
                                           const unsigned short* __restrict__ W1tG,
                                           float* __restrict__ out) {
    __shared__ unsigned short Bsh[21504];      // p1: [144][136] W~t ; p2: [128][168] Et
    __shared__ unsigned short srow[16][136];   // bf16 s rows (A of z-GEMM)
    __shared__ unsigned short zsh[16][168];    // bf16 z_aug rows (A of h-GEMM), K-pad
    __shared__ float wtld[S];
    __shared__ float tsh[16];
    __shared__ float red[4][16][3];
    const int tid = threadIdx.x;
    const int wave = tid >> 6;
    const int lane = tid & 63;
    const int n0 = blockIdx.x * 16;
    const int mrow = lane & 15;
    const int kch = lane >> 4;

    // --- prefetch Et into registers (hides latency under staging) ---
    uint4 etr[9];
    {
        const uint4* esrc = (const uint4*)EtG;
#pragma unroll
        for (int i = 0; i < 9; ++i)
            etr[i] = esrc[tid + 256 * i];
    }
    // --- stage W1t (pre-transposed) into Bsh-p1: pure uint4 copies ---
    {
        const uint4* src = (const uint4*)W1tG;
#pragma unroll
        for (int i = 0; i < 9; ++i) {
            const int idx = tid + 256 * i;     // 2304 uint4
            const int row = idx >> 4;          // u
            const int c8 = (idx & 15) * 8;     // q
            *(uint4*)&Bsh[row * 136 + c8] = src[idx];
        }
    }
    // --- stage s rows as bf16 (verified R13) ---
    {
        const int r = tid >> 4, q0 = (tid & 15) * 8;
        const float* p = feat + (size_t)(n0 + r) * 512 + q0;
        const float4 f0 = *(const float4*)(p);
        const float4 f1 = *(const float4*)(p + 4);
        const __hip_bfloat162 p0 = __float22bfloat162_rn(make_float2(f0.x, f0.y));
        const __hip_bfloat162 p1 = __float22bfloat162_rn(make_float2(f0.z, f0.w));
        const __hip_bfloat162 p2 = __float22bfloat162_rn(make_float2(f1.x, f1.y));
        const __hip_bfloat162 p3 = __float22bfloat162_rn(make_float2(f1.z, f1.w));
        uint4 pk;
        pk.x = *(const unsigned*)&p0;
        pk.y = *(const unsigned*)&p1;
        pk.z = *(const unsigned*)&p2;
        pk.w = *(const unsigned*)&p3;
        *(uint4*)&srow[r][q0] = pk;
    }
    // --- wtld (f32), coalesced per p ---
    if (tid < S) {
        float a = 0.f;
#pragma unroll
        for (int p = 0; p < 16; ++p)
            a = fmaf(Wt[p], W1s[p * S + tid], a);
        wtld[tid] = a;
    }
    // --- zsh K-pad cols 144..159 = 0 ---
    if (tid < 64) {
        const int row = tid >> 2, c4 = 144 + (tid & 3) * 4;
        *(unsigned long long*)&zsh[row][c4] = 0ULL;
    }
    if (tid < 16) tsh[tid] = times[n0 + tid];
    __syncthreads();

    // --- z-GEMM: z[n][u] = sum_q s[n,q]*W~t[u][q]; u-tiles split over waves ---
    {
        bf16x8 Af[4];
#pragma unroll
        for (int kk = 0; kk < 4; ++kk)
            Af[kk] = *(const bf16x8*)&srow[mrow][kk * 32 + kch * 8];
        const int tstart = (wave == 0) ? 0 : (wave * 2 + 1);   // {0,3,5,7}
        const int tcnt = (wave == 0) ? 3 : 2;
        for (int tt = 0; tt < tcnt; ++tt) {
            const int ti = tstart + tt;
            f32x4 acc = {0.f, 0.f, 0.f, 0.f};
#pragma unroll
            for (int kk = 0; kk < 4; ++kk) {
                const bf16x8 bf = *(const bf16x8*)&Bsh[(ti * 16 + mrow) * 136 + kk * 32 + kch * 8];
                acc = __builtin_amdgcn_mfma_f32_16x16x32_bf16(Af[kk], bf, acc, 0, 0, 0);
            }
            const int u = ti * 16 + mrow;
            const float wu = wtld[u];
#pragma unroll
            for (int i = 0; i < 4; ++i) {
                const int n = kch * 4 + i;
                zsh[n][u] = f2bf(acc[i] + tsh[n] * wu);
            }
        }
    }
    __syncthreads();   // z-GEMM reads of Bsh-p1 + zsh writes complete

    // --- Bsh-p2: Et[c][u] (+ zero K-pad cols 144..159) ---
#pragma unroll
    for (int i = 0; i < 9; ++i) {
        const int idx = tid + 256 * i;
        const int c = idx / 18;
        const int u8 = (idx % 18) * 8;
        *(uint4*)&Bsh[c * 168 + u8] = etr[i];
    }
    {
        const uint4 z4 = {0u, 0u, 0u, 0u};
        const int c = tid >> 1, u8 = 144 + (tid & 1) * 8;
        *(uint4*)&Bsh[c * 168 + u8] = z4;
    }
    __syncthreads();   // Et staged, zsh visible to all waves

    // --- h-GEMM: h[n][c] = sum_u z_aug[n,u]*Et[c][u], K=160 (padded) ---
    f32x4 acc0 = {0.f, 0.f, 0.f, 0.f};
    f32x4 acc1 = {0.f, 0.f, 0.f, 0.f};
#pragma unroll
    for (int kk = 0; kk < 5; ++kk) {
        const bf16x8 af = *(const bf16x8*)&zsh[mrow][kk * 32 + kch * 8];
        const bf16x8 bf0 = *(const bf16x8*)&Bsh[(32 * wave + mrow) * 168 + kk * 32 + kch * 8];
        const bf16x8 bf1 = *(const bf16x8*)&Bsh[(32 * wave + 16 + mrow) * 168 + kk * 32 + kch * 8];
        acc0 = __builtin_amdgcn_mfma_f32_16x16x32_bf16(af, bf0, acc0, 0, 0, 0);
        acc1 = __builtin_amdgcn_mfma_f32_16x16x32_bf16(af, bf1, acc1, 0, 0, 0);
    }

    // --- epilogue (bias folded into z_aug) ---
    float pm[4][3];
#pragma unroll
    for (int i = 0; i < 4; ++i) {
        const int nr = kch * 4 + i;
        const float h0 = acc0[i];
        const float h1 = acc1[i];
        const float* vp0 = feat + (size_t)(n0 + nr) * 512 + V + 3 * (32 * wave + mrow);
        const float* vp1 = vp0 + 48;
#pragma unroll
        for (int m = 0; m < 3; ++m)
            pm[i][m] = vp0[m] * h0 + vp1[m] * h1;
    }
#pragma unroll
    for (int i = 0; i < 4; ++i) {
#pragma unroll
        for (int m = 0; m < 3; ++m) {
            float v = pm[i][m];
            v += __shfl_xor(v, 1, 64);
            v += __shfl_xor(v, 2, 64);
            v += __shfl_xor(v, 4, 64);
            v += __shfl_xor(v, 8, 64);
            pm[i][m] = v;
        }
        if (mrow == 0) {
            const int nr = kch * 4 + i;
            red[wave][nr][0] = pm[i][0];
            red[wave][nr][1] = pm[i][1];
            red[wave][nr][2] = pm[i][2];
        }
    }
    __syncthreads();
    if (tid < 48) {
        const int nr = tid / 3, m = tid % 3;
        out[(size_t)(n0 + nr) * 3 + m] =
            red[0][nr][m] + red[1][nr][m] + red[2][nr][m] + red[3][nr][m];
    }
}

extern "C" void kernel_launch(void* const* d_in, const int* in_sizes, int n_in,
                              void* d_out, int out_size, void* d_ws, size_t ws_size,
                              hipStream_t stream) {
    const float* feat  = (const float*)d_in[0];  // [4096, 512]
    const float* times = (const float*)d_in[1];  // [4096, 1]
    const float* Wt    = (const float*)d_in[2];  // [1,16]
    const float* W1s   = (const float*)d_in[3];  // [144,144]
    const float* W1v   = (const float*)d_in[4];  // [128,128]
    // d_in[5] = Wss  -- dead path
    const float* Wsv   = (const float*)d_in[6];  // [144,128,128]
    // d_in[7] = Wvv  -- dead path
    const float* W2    = (const float*)d_in[8];  // [128,1]

    unsigned short* Et   = (unsigned short*)d_ws;   // [128][144] bf16
    unsigned short* W1tb = Et + 18432;              // [144][128] bf16
    unsigned* W1tb32     = (unsigned*)W1tb;

    kE<<<dim3(146), dim3(256), 0, stream>>>(Wsv, W2, W1v, W1s, Et, W1tb32);
    k4c<<<dim3(256), dim3(256), 0, stream>>>(feat, times, Wt, W1s, Et, W1tb,
                                             (float*)d_out);
}

// Round 20
// 17.774 us; speedup vs baseline: 1.1131x; 1.1131x over previous
//
#include <hip/hip_runtime.h>
#include <hip/hip_bf16.h>
#include <math.h>

// MACE equivariant score head — 2 nodes, NO fences/atomics. (R16, verified 17.6us)
//   + __syncthreads() between M-GEMM and h-GEMM (kills LDS ordering hazard)
//   + Ash rows 129..143 zero-filled (no garbage into MFMA)
// Dead code: Wss (d_in[5]), Wvv (d_in[7]) — s3=silu(s2) is deleted in the reference.
//
// out[n,m] = sum_c vraw[n,c,m] * h[n,c]
// h[n,c]   = t[n]*b[c] + sum_q s[n,q] * M[q,c]
//   E[u,c] = scale * sum_v D[u,v] * W1v[c,v],  D[u,v] = dot(Wsv[u,v,:], W2)
//   M[q,c] = sum_u W~aug[q,u] * E[u,c]   (q=0..127: W1s[16+q,u]; q=128 row -> b)
//   scale  = 1/(S*V*sqrt(V))

#define S 144
#define V 128

typedef __attribute__((ext_vector_type(8))) short bf16x8;
typedef __attribute__((ext_vector_type(4))) float f32x4;

// ---------------- kE: Et[c][u] (bf16) from Wsv slab u ----------------
__global__ __launch_bounds__(256) void kE(const float* __restrict__ Wsv,
                                          const float* __restrict__ W2,
                                          const float* __restrict__ W1v,
                                          unsigned short* __restrict__ Et) {
    __shared__ float Dsh[V];
    __shared__ float Epart[2][V];
    const int tid = threadIdx.x;
    const int wave = tid >> 6;
    const int lane = tid & 63;
    const int half = lane >> 5;
    const int j = lane & 31;
    const int u = blockIdx.x;

    const float4* Wsv4 = (const float4*)Wsv;
    const float4 w4 = ((const float4*)W2)[j];
    const size_t base4 = ((size_t)u * V + 32 * wave) * 32;
    float4 a[16];
#pragma unroll
    for (int i = 0; i < 16; ++i)
        a[i] = Wsv4[base4 + (size_t)(2 * i + half) * 32 + j];
#pragma unroll
    for (int i = 0; i < 16; ++i) {
        float acc = a[i].x * w4.x + a[i].y * w4.y + a[i].z * w4.z + a[i].w * w4.w;
#pragma unroll
        for (int off = 1; off < 32; off <<= 1)
            acc += __shfl_xor(acc, off, 64);
        if (j == 0) Dsh[32 * wave + 2 * i + half] = acc;
    }
    __syncthreads();

    const int c = tid & 127, vh = tid >> 7;
    const float4* W1v4 = (const float4*)W1v;
    const float4* D4 = (const float4*)Dsh;
    float acc = 0.f;
#pragma unroll
    for (int i = 0; i < 16; ++i) {
        const float4 wv = W1v4[c * 32 + vh * 16 + i];
        const float4 dv = D4[vh * 16 + i];
        acc += wv.x * dv.x + wv.y * dv.y + wv.z * dv.z + wv.w * dv.w;
    }
    Epart[vh][c] = acc;
    __syncthreads();
    if (tid < V) {
        const float scale = 1.0f / (144.0f * 128.0f * sqrtf(128.0f));
        const float val = scale * (Epart[0][tid] + Epart[1][tid]);
        const __hip_bfloat16 hb = __float2bfloat16(val);
        Et[(size_t)tid * S + u] = *(const unsigned short*)&hb;   // [c][u]
    }
}

// ---------------- k4b: per-block M-GEMM + h-GEMM + epilogue ----------------
__global__ __launch_bounds__(256) void k4b(const float* __restrict__ feat,
                                           const float* __restrict__ times,
                                           const float* __restrict__ Wt,
                                           const float* __restrict__ W1s,
                                           const unsigned short* __restrict__ EtG,
                                           float* __restrict__ out) {
    __shared__ unsigned short Ash[144][168];   // W~aug[q][u], K-pad zeros
    __shared__ unsigned short Etsh[128][168];  // Et[c][u], K-pad zeros
    __shared__ unsigned short Mtsh[128][136];  // M^T[c][q]
    __shared__ unsigned short srow[16][136];   // bf16 s rows
    __shared__ float bsh[128];
    __shared__ float tsh[16];
    __shared__ float red[4][16][3];
    const int tid = threadIdx.x;
    const int wave = tid >> 6;
    const int lane = tid & 63;
    const int n0 = blockIdx.x * 16;
    const int mrow = lane & 15;
    const int kch = lane >> 4;

    // --- stage W~ rows 0..127: 4608 float4 / 256 thr = 18 each ---
#pragma unroll
    for (int i = 0; i < 18; ++i) {
        const int idx = tid + 256 * i;
        const int row = idx / 36;
        const int c4 = (idx % 36) * 4;
        const float4 f = *(const float4*)(W1s + (size_t)(16 + row) * S + c4);
        const __hip_bfloat162 p0 = __float22bfloat162_rn(make_float2(f.x, f.y));
        const __hip_bfloat162 p1 = __float22bfloat162_rn(make_float2(f.z, f.w));
        uint2 pk;
        pk.x = *(const unsigned*)&p0;
        pk.y = *(const unsigned*)&p1;
        *(uint2*)&Ash[row][c4] = pk;
    }
    // --- row 128 = wtld[u] ---
    if (tid < S) {
        float a = 0.f;
#pragma unroll
        for (int p = 0; p < 16; ++p)
            a = fmaf(Wt[p], W1s[p * S + tid], a);
        const __hip_bfloat16 hb = __float2bfloat16(a);
        Ash[128][tid] = *(const unsigned short*)&hb;
    }
    // --- zero K-pad cols 144..167 (Ash rows 0..128, Etsh rows 0..127) ---
    for (int i = tid; i < 864; i += 256) {
        const int row = i / 6, c4 = 144 + (i % 6) * 4;
        *(unsigned long long*)&Ash[row][c4] = 0ULL;
    }
    for (int i = tid; i < 768; i += 256) {
        const int row = i / 6, c4 = 144 + (i % 6) * 4;
        *(unsigned long long*)&Etsh[row][c4] = 0ULL;
    }
    // --- zero Ash rows 129..143 entirely (15 rows x 21 uint4) ---
    {
        const uint4 z4 = {0u, 0u, 0u, 0u};
        for (int i = tid; i < 315; i += 256) {
            const int row = 129 + i / 21;
            const int c8 = (i % 21) * 8;
            *(uint4*)&Ash[row][c8] = z4;
        }
    }
    // --- stage Et: 2304 uint4 / 256 thr = 9 each ---
    {
        const uint4* src = (const uint4*)EtG;
#pragma unroll
        for (int i = 0; i < 9; ++i) {
            const int idx = tid + 256 * i;
            const int row = idx / 18;            // c
            const int c8 = (idx % 18) * 8;       // u
            *(uint4*)&Etsh[row][c8] = src[idx];
        }
    }
    // --- stage s rows as bf16 (R13) ---
    {
        const int r = tid >> 4, q0 = (tid & 15) * 8;
        const float* p = feat + (size_t)(n0 + r) * 512 + q0;
        const float4 f0 = *(const float4*)(p);
        const float4 f1 = *(const float4*)(p + 4);
        const __hip_bfloat162 p0 = __float22bfloat162_rn(make_float2(f0.x, f0.y));
        const __hip_bfloat162 p1 = __float22bfloat162_rn(make_float2(f0.z, f0.w));
        const __hip_bfloat162 p2 = __float22bfloat162_rn(make_float2(f1.x, f1.y));
        const __hip_bfloat162 p3 = __float22bfloat162_rn(make_float2(f1.z, f1.w));
        uint4 pk;
        pk.x = *(const unsigned*)&p0;
        pk.y = *(const unsigned*)&p1;
        pk.z = *(const unsigned*)&p2;
        pk.w = *(const unsigned*)&p3;
        *(uint4*)&srow[r][q0] = pk;
    }
    if (tid < 16) tsh[tid] = times[n0 + tid];
    __syncthreads();

    // --- GEMM-M: M[q][c] = sum_u Ash[q][u]*Etsh[c][u], wave w -> c in [32w,32w+32) ---
    bf16x8 Bf[2][5];
#pragma unroll
    for (int c2 = 0; c2 < 2; ++c2)
#pragma unroll
        for (int kk = 0; kk < 5; ++kk)
            Bf[c2][kk] = *(const bf16x8*)&Etsh[(2 * wave + c2) * 16 + mrow][kk * 32 + kch * 8];

#pragma unroll
    for (int rt = 0; rt < 9; ++rt) {
        bf16x8 Af[5];
#pragma unroll
        for (int kk = 0; kk < 5; ++kk)
            Af[kk] = *(const bf16x8*)&Ash[rt * 16 + mrow][kk * 32 + kch * 8];
#pragma unroll
        for (int c2 = 0; c2 < 2; ++c2) {
            f32x4 acc = {0.f, 0.f, 0.f, 0.f};
#pragma unroll
            for (int kk = 0; kk < 5; ++kk)
                acc = __builtin_amdgcn_mfma_f32_16x16x32_bf16(Af[kk], Bf[c2][kk], acc, 0, 0, 0);
            const int c = (2 * wave + c2) * 16 + mrow;
            if (rt < 8) {
#pragma unroll
                for (int i = 0; i < 4; ++i) {
                    const int q = rt * 16 + kch * 4 + i;
                    const __hip_bfloat16 hb = __float2bfloat16(acc[i]);
                    Mtsh[c][q] = *(const unsigned short*)&hb;
                }
            } else if (kch == 0) {
                bsh[c] = acc[0];      // q = 128 row -> b[c], f32
            }
        }
    }
    __syncthreads();   // make all Mtsh/bsh writes visible — removes ordering hazard

    // --- h-GEMM (R13 verbatim, Mtsh/bsh sources) ---
    const float bc0 = bsh[32 * wave + mrow];
    const float bc1 = bsh[32 * wave + 16 + mrow];
    f32x4 acc0 = {0.f, 0.f, 0.f, 0.f};
    f32x4 acc1 = {0.f, 0.f, 0.f, 0.f};
#pragma unroll
    for (int kk = 0; kk < 4; ++kk) {
        const bf16x8 af = *(const bf16x8*)&srow[mrow][kk * 32 + kch * 8];
        const bf16x8 bf0 = *(const bf16x8*)&Mtsh[32 * wave + mrow][kk * 32 + kch * 8];
        const bf16x8 bf1 = *(const bf16x8*)&Mtsh[32 * wave + 16 + mrow][kk * 32 + kch * 8];
        acc0 = __builtin_amdgcn_mfma_f32_16x16x32_bf16(af, bf0, acc0, 0, 0, 0);
        acc1 = __builtin_amdgcn_mfma_f32_16x16x32_bf16(af, bf1, acc1, 0, 0, 0);
    }

    float pm[4][3];
#pragma unroll
    for (int i = 0; i < 4; ++i) {
        const int nr = kch * 4 + i;
        const float t = tsh[nr];
        const float h0 = acc0[i] + t * bc0;
        const float h1 = acc1[i] + t * bc1;
        const float* vp0 = feat + (size_t)(n0 + nr) * 512 + V + 3 * (32 * wave + mrow);
        const float* vp1 = vp0 + 48;
#pragma unroll
        for (int m = 0; m < 3; ++m)
            pm[i][m] = vp0[m] * h0 + vp1[m] * h1;
    }
#pragma unroll
    for (int i = 0; i < 4; ++i) {
#pragma unroll
        for (int m = 0; m < 3; ++m) {
            float v = pm[i][m];
            v += __shfl_xor(v, 1, 64);
            v += __shfl_xor(v, 2, 64);
            v += __shfl_xor(v, 4, 64);
            v += __shfl_xor(v, 8, 64);
            pm[i][m] = v;
        }
        if (mrow == 0) {
            const int nr = kch * 4 + i;
            red[wave][nr][0] = pm[i][0];
            red[wave][nr][1] = pm[i][1];
            red[wave][nr][2] = pm[i][2];
        }
    }
    __syncthreads();
    if (tid < 48) {
        const int nr = tid / 3, m = tid % 3;
        out[(size_t)(n0 + nr) * 3 + m] =
            red[0][nr][m] + red[1][nr][m] + red[2][nr][m] + red[3][nr][m];
    }
}

extern "C" void kernel_launch(void* const* d_in, const int* in_sizes, int n_in,
                              void* d_out, int out_size, void* d_ws, size_t ws_size,
                              hipStream_t stream) {
    const float* feat  = (const float*)d_in[0];  // [4096, 512]
    const float* times = (const float*)d_in[1];  // [4096, 1]
    const float* Wt    = (const float*)d_in[2];  // [1,16]
    const float* W1s   = (const float*)d_in[3];  // [144,144]
    const float* W1v   = (const float*)d_in[4];  // [128,128]
    // d_in[5] = Wss  -- dead path
    const float* Wsv   = (const float*)d_in[6];  // [144,128,128]
    // d_in[7] = Wvv  -- dead path
    const float* W2    = (const float*)d_in[8];  // [128,1]

    unsigned short* Et = (unsigned short*)d_ws;   // [128][144] bf16

    kE<<<dim3(144), dim3(256), 0, stream>>>(Wsv, W2, W1v, Et);
    k4b<<<dim3(256), dim3(256), 0, stream>>>(feat, times, Wt, W1s, Et, (float*)d_out);
}